// Round 16
// baseline (107.074 us; speedup 1.0000x reference)
//
#include <hip/hip_runtime.h>
#include <hip/hip_bf16.h>
#include <math.h>

// ---------------- problem constants ----------------
#define SEQ   4096
#define EMB   1024
#define NH    8
#define HD    128
#define NSLOT 15   // distinct gathered positions: 0..10, S-4..S-1 (+1 zero pad slot = 16)

typedef __attribute__((ext_vector_type(8))) short bf16x8;
typedef __attribute__((ext_vector_type(4))) float f32x4;
typedef __attribute__((ext_vector_type(4))) unsigned short ushort4v;
typedef unsigned short ushort_t;

// per-t slot multiplicity masks, 2 bits per slot (slot s at bits 2s..2s+1).
__device__ __constant__ unsigned int MULT[8] = {
    0x00005555u,  // t=0:   slots {0..7}
    0x10015055u,  // t=1:   {0,1,2,3,6,7,8,14}
    0x14050055u,  // t=2:   {0,1,2,3,8,9,13,14}
    0x15100055u,  // t=3:   {0,1,2,3,10,12,13,14}
    0x15800015u,  // t=S-3: {0,1,2, 11x2, 12,13,14}
    0x16800005u,  // t=S-2: {0,1, 11x2, 12x2, 13,14}
    0x1A800001u,  // t=S-1: {0, 11x2, 12x2, 13x2, 14}
    0x15400055u   // interior: {0,1,2,3,11,12,13,14}
};

__device__ __forceinline__ unsigned short f2bf(float x) {
    unsigned int u = __float_as_uint(x);
    return (unsigned short)((u + 0x7FFFu + ((u >> 16) & 1u)) >> 16);
}

// 8x fp32 -> bf16x8 via v_cvt_pk_bf16_f32 (RNE; no builtin on gfx950)
__device__ __forceinline__ bf16x8 cvt8(float4 a, float4 b) {
    union { unsigned int u[4]; bf16x8 v; } r;
    asm("v_cvt_pk_bf16_f32 %0, %1, %2" : "=v"(r.u[0]) : "v"(a.x), "v"(a.y));
    asm("v_cvt_pk_bf16_f32 %0, %1, %2" : "=v"(r.u[1]) : "v"(a.z), "v"(a.w));
    asm("v_cvt_pk_bf16_f32 %0, %1, %2" : "=v"(r.u[2]) : "v"(b.x), "v"(b.y));
    asm("v_cvt_pk_bf16_f32 %0, %1, %2" : "=v"(r.u[3]) : "v"(b.z), "v"(b.w));
    return r.v;
}

// async global->LDS, 16B per lane; lds ptr must be wave-uniform
__device__ __forceinline__ void gld16f(const float* g, float* l) {
    __builtin_amdgcn_global_load_lds(
        (const __attribute__((address_space(1))) unsigned int*)g,
        (__attribute__((address_space(3))) unsigned int*)l, 16, 0, 0);
}
__device__ __forceinline__ void gld16u(const ushort_t* g, ushort_t* l) {
    __builtin_amdgcn_global_load_lds(
        (const __attribute__((address_space(1))) unsigned int*)g,
        (__attribute__((address_space(3))) unsigned int*)l, 16, 0, 0);
}

// bijective chunked XCD swizzle (nwg % 8 == 0)
__device__ __forceinline__ int xcd_swz(int bid, int nwg) {
    int cpx = nwg >> 3;
    return (bid & 7) * cpx + (bid >> 3);
}

// ---------------- small k/v projection (fp32): kvp[(b*2+kv)*15+slot][1024] ----------------
__global__ __launch_bounds__(256) void proj_kv_small(
    const float* __restrict__ k, const float* __restrict__ v,
    const float* __restrict__ ipw, const float* __restrict__ ipb,
    float* __restrict__ kvp) {
    int fc  = blockIdx.x & 63;
    int bkv = blockIdx.x >> 6;
    int kv  = bkv & 1;
    int b   = bkv >> 1;

    const float* x0 = (kv ? v : k) + (size_t)b * SEQ * EMB;
    const float* Wm = ipw + (size_t)(1 + kv) * EMB * EMB;
    const float* bb = ipb + (size_t)(1 + kv) * EMB;

    __shared__ __align__(16) float xs[NSLOT][EMB];
    int tid = threadIdx.x;
#pragma unroll
    for (int i = 0; i < NSLOT; i++) {
        int pos = (i < 11) ? i : (SEQ - 4 + (i - 11));
        *(float4*)&xs[i][tid * 4] = *(const float4*)&x0[(size_t)pos * EMB + tid * 4];
    }
    __syncthreads();

    if (tid < 240) {
        int row  = tid >> 4;           // slot 0..14
        int feat = fc * 16 + (tid & 15);
        const float* wrow = Wm + (size_t)feat * EMB;
        float acc0 = 0.f, acc1 = 0.f;
#pragma unroll 4
        for (int kk = 0; kk < EMB; kk += 8) {
            float4 xv0 = *(const float4*)&xs[row][kk];
            float4 wv0 = *(const float4*)&wrow[kk];
            float4 xv1 = *(const float4*)&xs[row][kk + 4];
            float4 wv1 = *(const float4*)&wrow[kk + 4];
            acc0 += xv0.x * wv0.x + xv0.y * wv0.y + xv0.z * wv0.z + xv0.w * wv0.w;
            acc1 += xv1.x * wv1.x + xv1.y * wv1.y + xv1.z * wv1.z + xv1.w * wv1.w;
        }
        kvp[((size_t)((b * 2 + kv) * NSLOT + row)) * EMB + feat] = acc0 + acc1 + bb[feat];
    }
}

// ---------------- merged precompute: G/cvec (gmat part) + UT (umat part) ----------------
// LDS: 1 KB only -> occupancy unconstrained. umat: no staging (kvp is L2-hot),
// float4 loads, 2 acc chains (short dependency chains, many loads in flight).
__global__ __launch_bounds__(256) void gu_pre(
    const float* __restrict__ kvp, const float* __restrict__ ipw,
    const float* __restrict__ ipb, const float* __restrict__ outw,
    ushort_t* __restrict__ G, float* __restrict__ cvec,
    ushort_t* __restrict__ UT, int nGm) {
    __shared__ float xs[HD];
    __shared__ float red[HD];
    int tid = threadIdx.x;

    if (blockIdx.x < (unsigned)nGm) {
        // ---- gmat: G[b][hs][e] = Wq_h^T kh_h[s]; cvec = bq_h . kh_h[s] ----
        int hs = blockIdx.x & 127, b = blockIdx.x >> 7;
        int h = hs >> 4, s = hs & 15;
        if (tid < HD)
            xs[tid] = (s < NSLOT)
                ? kvp[((size_t)((b * 2 + 0) * NSLOT + s)) * EMB + h * HD + tid] : 0.f;
        __syncthreads();
        int e0 = tid * 4;
        float a0 = 0.f, a1 = 0.f, a2 = 0.f, a3 = 0.f;
        float b0 = 0.f, b1 = 0.f, b2 = 0.f, b3 = 0.f;    // second chain
#pragma unroll 4
        for (int d = 0; d < HD; d += 2) {
            float xv0 = xs[d], xv1 = xs[d + 1];
            const float* w0 = ipw + (size_t)(h * HD + d) * EMB + e0;
            const float* w1 = w0 + EMB;
            float4 wv0 = *(const float4*)w0;
            float4 wv1 = *(const float4*)w1;
            a0 += xv0 * wv0.x; a1 += xv0 * wv0.y; a2 += xv0 * wv0.z; a3 += xv0 * wv0.w;
            b0 += xv1 * wv1.x; b1 += xv1 * wv1.y; b2 += xv1 * wv1.z; b3 += xv1 * wv1.w;
        }
        ushort4v gv;
        gv[0] = f2bf(a0 + b0); gv[1] = f2bf(a1 + b1);
        gv[2] = f2bf(a2 + b2); gv[3] = f2bf(a3 + b3);
        *(ushort4v*)&G[((size_t)b * 128 + hs) * EMB + e0] = gv;

        if (tid < HD) red[tid] = xs[tid] * ipb[h * HD + tid];
        __syncthreads();
        if (tid < 64) {
            float vsum = red[tid] + red[tid + 64];
            vsum += __shfl_down(vsum, 32, 64); vsum += __shfl_down(vsum, 16, 64);
            vsum += __shfl_down(vsum, 8, 64);  vsum += __shfl_down(vsum, 4, 64);
            vsum += __shfl_down(vsum, 2, 64);  vsum += __shfl_down(vsum, 1, 64);
            if (tid == 0) cvec[b * 128 + hs] = vsum;
        }
    } else {
        // ---- umat: UT[b][e][h*16+s] = vh_h[s] . Wo[e, hHD..]; thread=(s, e_local) ----
        int idx = blockIdx.x - nGm;
        int ec = idx & 63, b = idx >> 6;
        int s = tid & 15, el = tid >> 4;
        int e = ec * 16 + el;
        const float* vbase = kvp + ((size_t)((b * 2 + 1) * NSLOT + (s < NSLOT ? s : 0))) * EMB;
        const float* orow0 = outw + (size_t)e * EMB;
#pragma unroll
        for (int h = 0; h < NH; h++) {
            float acc0 = 0.f, acc1 = 0.f;
            if (s < NSLOT) {
                const float* orow = orow0 + h * HD;
                const float* vrow = vbase + h * HD;
#pragma unroll 4
                for (int d = 0; d < HD; d += 8) {
                    float4 o0 = *(const float4*)&orow[d];
                    float4 v0 = *(const float4*)&vrow[d];
                    float4 o1 = *(const float4*)&orow[d + 4];
                    float4 v1 = *(const float4*)&vrow[d + 4];
                    acc0 += o0.x * v0.x + o0.y * v0.y + o0.z * v0.z + o0.w * v0.w;
                    acc1 += o1.x * v1.x + o1.y * v1.y + o1.z * v1.z + o1.w * v1.w;
                }
            }
            UT[((size_t)b * EMB + e) * 128 + h * 16 + s] = f2bf(acc0 + acc1);
        }
    }
}

// ---------------- fused scores + softmax + output GEMM (R14-verbatim, PASSED) ----------------
// Block = 16 t-rows, 256 threads (4 waves), grid 512 (2 blocks/CU).
// Per K-tile: q AND G staged via coalesced global_load_lds into a SINGLE buffer,
// proven 2-barrier m97 structure (__syncthreads both sides — full memory fence).
#define TBM 16
#define NTQ 16
__global__ __launch_bounds__(256) void score_out(
    const float* __restrict__ q, const ushort_t* __restrict__ G,
    const float* __restrict__ cvec, const ushort_t* __restrict__ UT,
    const float* __restrict__ outb, float* __restrict__ out) {
    __shared__ __align__(16) union {
        struct { float qs[TBM * 64]; ushort_t gs[128 * 64]; } s1;  // 4+16 KB
        ushort_t pl[TBM * 128];                                    // 4 KB
    } sm;

    int tid = threadIdx.x, lane = tid & 63, w = tid >> 6;
    int fr = lane & 15, g = lane >> 4;
    int lb  = xcd_swz(blockIdx.x, gridDim.x);
    int mb0 = lb * TBM;
    int b   = mb0 >> 12;

    const ushort_t* Gb = G + (size_t)b * 128 * EMB;
    int hsb = w * 32;                    // wave w covers heads 2w, 2w+1
    float cv0 = cvec[b * 128 + hsb + fr];
    float cv1 = cvec[b * 128 + hsb + 16 + fr];

    // staging coords (per lane), inverse-swizzled global sources (rule #21)
    int qrow = w * 4 + (lane >> 4);              // wave w stages q rows w*4..w*4+3
    int qlg  = (lane & 15) ^ qrow;               // logical granule (4 f32), 4-bit XOR
    const float* qsrc = q + (size_t)(mb0 + qrow) * EMB + qlg * 4;
    int grow = w * 8 + (lane >> 3);              // row within 32-row issue group
    int glg  = (lane & 7) ^ (grow & 7);          // logical granule (8 bf16), 3-bit XOR

    f32x4 acc[2] = {};

    for (int t = 0; t < NTQ; t++) {
        __syncthreads();                         // WAR: all reads of prev tile done
        gld16f(qsrc + t * 64, &sm.s1.qs[w * 256]);
#pragma unroll
        for (int j = 0; j < 4; j++)
            gld16u(Gb + (size_t)(j * 32 + grow) * EMB + t * 64 + glg * 8,
                   &sm.s1.gs[(j * 32 + w * 8) * 64]);
        __syncthreads();                         // full drain: tile visible to all

        const float*    qb = sm.s1.qs;
        const ushort_t* gb = sm.s1.gs;
        __builtin_amdgcn_s_setprio(1);
#pragma unroll
        for (int sub = 0; sub < 2; sub++) {
            int lg0 = sub * 8 + g * 2;
            float4 x0 = *(const float4*)&qb[fr * 64 + ((lg0)     ^ fr) * 4];
            float4 x1 = *(const float4*)&qb[fr * 64 + ((lg0 + 1) ^ fr) * 4];
            bf16x8 af = cvt8(x0, x1);
#pragma unroll
            for (int n = 0; n < 2; n++) {
                int row = hsb + n * 16 + fr;
                bf16x8 bf_ = *(const bf16x8*)&gb[row * 64 + (((sub * 4 + g) ^ (fr & 7)) * 8)];
                acc[n] = __builtin_amdgcn_mfma_f32_16x16x32_bf16(af, bf_, acc[n], 0, 0, 0);
            }
        }
        __builtin_amdgcn_s_setprio(0);
    }

    __syncthreads();   // all s1 reads done before pl-union overwrite

    // ---- softmax (per (t, head) over 16 slots = 16 lanes) -> P in LDS ----
    const float scale = 0.08838834764831845f;   // 1/sqrt(128)
#pragma unroll
    for (int r = 0; r < 4; r++) {
        int row = g * 4 + r;
        int tl  = (mb0 + row) & (SEQ - 1);
        int cse = (tl >= 4 && tl <= SEQ - 4) ? 7 : ((tl < 4) ? tl : tl - (SEQ - 3) + 4);
        float mult = (float)((MULT[cse] >> (fr * 2)) & 3u);
#pragma unroll
        for (int n = 0; n < 2; n++) {
            float vv = (acc[n][r] + (n ? cv1 : cv0)) * scale;
            float vm = (mult != 0.f) ? vv : -1e30f;
#pragma unroll
            for (int sh = 1; sh < 16; sh <<= 1) vm = fmaxf(vm, __shfl_xor(vm, sh, 64));
            float e_ = mult * expf(vv - vm);
            float z = e_;
#pragma unroll
            for (int sh = 1; sh < 16; sh <<= 1) z += __shfl_xor(z, sh, 64);
            int col = hsb + n * 16 + fr;
            int cg  = col >> 3;
            int pg  = (cg & 8) | ((cg & 7) ^ (row & 7));   // granule XOR swizzle
            sm.pl[row * 128 + pg * 8 + (col & 7)] = f2bf(e_ / z);
        }
    }
    __syncthreads();

    // ---- phase 2: out(16 rows x 256 e per wave) = P @ UT^T + outb ----
    const ushort_t* UTb = UT + (size_t)b * EMB * 128;
    int eb = w * 256;
#pragma unroll 4
    for (int n = 0; n < 16; n++) {
        int e = eb + n * 16 + fr;
        f32x4 o2 = {};
#pragma unroll
        for (int kk = 0; kk < 4; kk++) {
            int gi = kk * 4 + g;
            bf16x8 ub = *(const bf16x8*)&UTb[(size_t)e * 128 + kk * 32 + g * 8];
            int pg = (gi & 8) | ((gi & 7) ^ (fr & 7));
            bf16x8 pa = *(const bf16x8*)&sm.pl[fr * 128 + pg * 8];
            o2 = __builtin_amdgcn_mfma_f32_16x16x32_bf16(pa, ub, o2, 0, 0, 0);
        }
        float bn = outb[e];
#pragma unroll
        for (int r = 0; r < 4; r++)
            out[(size_t)(mb0 + g * 4 + r) * EMB + e] = o2[r] + bn;
    }
}

// ---------------- launcher ----------------
extern "C" void kernel_launch(void* const* d_in, const int* in_sizes, int n_in,
                              void* d_out, int out_size, void* d_ws, size_t ws_size,
                              hipStream_t stream) {
    const float* q    = (const float*)d_in[0];
    const float* k    = (const float*)d_in[1];
    const float* v    = (const float*)d_in[2];
    const float* ipw  = (const float*)d_in[3];
    const float* ipb  = (const float*)d_in[4];
    const float* outw = (const float*)d_in[5];
    const float* outb = (const float*)d_in[6];
    float* out = (float*)d_out;

    int Bb = in_sizes[0] / (SEQ * EMB);     // batch (=2)
    int M  = Bb * SEQ;                      // 8192

    float*    kvp  = (float*)d_ws;                                     // Bb*2*15*1024 f32
    ushort_t* G    = (ushort_t*)(kvp + (size_t)Bb * 2 * NSLOT * EMB);  // Bb*128*1024 bf16
    ushort_t* UTm  = G + (size_t)Bb * 128 * EMB;                       // Bb*1024*128 bf16
    float*    cvec = (float*)(UTm + (size_t)Bb * EMB * 128);           // Bb*128 f32

    proj_kv_small<<<dim3(Bb * 2 * 64), dim3(256), 0, stream>>>(k, v, ipw, ipb, kvp);
    gu_pre<<<dim3(Bb * 128 + Bb * 64), dim3(256), 0, stream>>>(
        kvp, ipw, ipb, outw, G, cvec, UTm, Bb * 128);
    score_out<<<dim3(M / TBM), dim3(256), 0, stream>>>(q, G, cvec, UTm, outb, out);
}

// Round 17
// 92.349 us; speedup vs baseline: 1.1595x; 1.1595x over previous
//
#include <hip/hip_runtime.h>
#include <hip/hip_bf16.h>
#include <math.h>

// ---------------- problem constants ----------------
#define SEQ   4096
#define EMB   1024
#define NH    8
#define HD    128
#define NSLOT 15   // distinct gathered positions: 0..10, S-4..S-1 (+1 zero pad slot = 16)

typedef __attribute__((ext_vector_type(8))) short bf16x8;
typedef __attribute__((ext_vector_type(4))) float f32x4;
typedef __attribute__((ext_vector_type(4))) unsigned short ushort4v;
typedef unsigned short ushort_t;

// per-t slot multiplicity masks, 2 bits per slot (slot s at bits 2s..2s+1).
__device__ __constant__ unsigned int MULT[8] = {
    0x00005555u,  // t=0:   slots {0..7}
    0x10015055u,  // t=1:   {0,1,2,3,6,7,8,14}
    0x14050055u,  // t=2:   {0,1,2,3,8,9,13,14}
    0x15100055u,  // t=3:   {0,1,2,3,10,12,13,14}
    0x15800015u,  // t=S-3: {0,1,2, 11x2, 12,13,14}
    0x16800005u,  // t=S-2: {0,1, 11x2, 12x2, 13,14}
    0x1A800001u,  // t=S-1: {0, 11x2, 12x2, 13x2, 14}
    0x15400055u   // interior: {0,1,2,3,11,12,13,14}
};

__device__ __forceinline__ unsigned short f2bf(float x) {
    unsigned int u = __float_as_uint(x);
    return (unsigned short)((u + 0x7FFFu + ((u >> 16) & 1u)) >> 16);
}

// 8x fp32 -> bf16x8 via v_cvt_pk_bf16_f32 (RNE; no builtin on gfx950)
__device__ __forceinline__ bf16x8 cvt8(float4 a, float4 b) {
    union { unsigned int u[4]; bf16x8 v; } r;
    asm("v_cvt_pk_bf16_f32 %0, %1, %2" : "=v"(r.u[0]) : "v"(a.x), "v"(a.y));
    asm("v_cvt_pk_bf16_f32 %0, %1, %2" : "=v"(r.u[1]) : "v"(a.z), "v"(a.w));
    asm("v_cvt_pk_bf16_f32 %0, %1, %2" : "=v"(r.u[2]) : "v"(b.x), "v"(b.y));
    asm("v_cvt_pk_bf16_f32 %0, %1, %2" : "=v"(r.u[3]) : "v"(b.z), "v"(b.w));
    return r.v;
}

// async global->LDS, 16B per lane; lds ptr must be wave-uniform
__device__ __forceinline__ void gld16f(const float* g, float* l) {
    __builtin_amdgcn_global_load_lds(
        (const __attribute__((address_space(1))) unsigned int*)g,
        (__attribute__((address_space(3))) unsigned int*)l, 16, 0, 0);
}
__device__ __forceinline__ void gld16u(const ushort_t* g, ushort_t* l) {
    __builtin_amdgcn_global_load_lds(
        (const __attribute__((address_space(1))) unsigned int*)g,
        (__attribute__((address_space(3))) unsigned int*)l, 16, 0, 0);
}

// bijective chunked XCD swizzle (nwg % 8 == 0)
__device__ __forceinline__ int xcd_swz(int bid, int nwg) {
    int cpx = nwg >> 3;
    return (bid & 7) * cpx + (bid >> 3);
}

// ---------------- small k/v projection (fp32): kvp[(b*2+kv)*15+slot][1024] ----------------
// R14-verbatim (PASSED in best config)
__global__ __launch_bounds__(256) void proj_kv_small(
    const float* __restrict__ k, const float* __restrict__ v,
    const float* __restrict__ ipw, const float* __restrict__ ipb,
    float* __restrict__ kvp) {
    int fc  = blockIdx.x & 63;
    int bkv = blockIdx.x >> 6;
    int kv  = bkv & 1;
    int b   = bkv >> 1;

    const float* x0 = (kv ? v : k) + (size_t)b * SEQ * EMB;
    const float* Wm = ipw + (size_t)(1 + kv) * EMB * EMB;
    const float* bb = ipb + (size_t)(1 + kv) * EMB;

    __shared__ __align__(16) float xs[NSLOT][EMB];
    int tid = threadIdx.x;
#pragma unroll
    for (int i = 0; i < NSLOT; i++) {
        int pos = (i < 11) ? i : (SEQ - 4 + (i - 11));
        *(float4*)&xs[i][tid * 4] = *(const float4*)&x0[(size_t)pos * EMB + tid * 4];
    }
    __syncthreads();

    if (tid < 240) {
        int row  = tid >> 4;           // slot 0..14
        int feat = fc * 16 + (tid & 15);
        const float* wrow = Wm + (size_t)feat * EMB;
        float acc = 0.f;
#pragma unroll 8
        for (int kk = 0; kk < EMB; kk += 4) {
            float4 xv = *(const float4*)&xs[row][kk];
            float4 wv = *(const float4*)&wrow[kk];
            acc += xv.x * wv.x + xv.y * wv.y + xv.z * wv.z + xv.w * wv.w;
        }
        kvp[((size_t)((b * 2 + kv) * NSLOT + row)) * EMB + feat] = acc + bb[feat];
    }
}

// ---------------- merged precompute: G/cvec (gmat part) + UT (umat part) ----------------
// R14-verbatim (PASSED in best config; staged umat avoids per-lane line-scatter)
union GUShared {
    struct { float xs[HD]; float red[HD]; } gm;
    float vs[NSLOT][EMB + 4];
};
__global__ __launch_bounds__(256) void gu_pre(
    const float* __restrict__ kvp, const float* __restrict__ ipw,
    const float* __restrict__ ipb, const float* __restrict__ outw,
    ushort_t* __restrict__ G, float* __restrict__ cvec,
    ushort_t* __restrict__ UT, int nGm) {
    __shared__ __align__(16) GUShared sm;
    int tid = threadIdx.x;

    if (blockIdx.x < (unsigned)nGm) {
        // ---- gmat: G[b][hs][e] = Wq_h^T kh_h[s]; cvec = bq_h . kh_h[s] ----
        int hs = blockIdx.x & 127, b = blockIdx.x >> 7;
        int h = hs >> 4, s = hs & 15;
        if (tid < HD)
            sm.gm.xs[tid] = (s < NSLOT)
                ? kvp[((size_t)((b * 2 + 0) * NSLOT + s)) * EMB + h * HD + tid] : 0.f;
        __syncthreads();
        int e0 = tid * 4;
        float a0 = 0.f, a1 = 0.f, a2 = 0.f, a3 = 0.f;
#pragma unroll 8
        for (int d = 0; d < HD; d++) {
            float xv = sm.gm.xs[d];
            const float* wr_ = ipw + (size_t)(h * HD + d) * EMB + e0;
            a0 += xv * wr_[0]; a1 += xv * wr_[1]; a2 += xv * wr_[2]; a3 += xv * wr_[3];
        }
        ushort4v gv; gv[0] = f2bf(a0); gv[1] = f2bf(a1); gv[2] = f2bf(a2); gv[3] = f2bf(a3);
        *(ushort4v*)&G[((size_t)b * 128 + hs) * EMB + e0] = gv;

        if (tid < HD) sm.gm.red[tid] = sm.gm.xs[tid] * ipb[h * HD + tid];
        __syncthreads();
        if (tid < 64) {
            float vsum = sm.gm.red[tid] + sm.gm.red[tid + 64];
            vsum += __shfl_down(vsum, 32, 64); vsum += __shfl_down(vsum, 16, 64);
            vsum += __shfl_down(vsum, 8, 64);  vsum += __shfl_down(vsum, 4, 64);
            vsum += __shfl_down(vsum, 2, 64);  vsum += __shfl_down(vsum, 1, 64);
            if (tid == 0) cvec[b * 128 + hs] = vsum;
        }
    } else {
        // ---- umat: UT[b][e][hs] = vh_h[s] . Wo[e, hHD..]  (LDS-staged vs) ----
        int idx = blockIdx.x - nGm;
        int ec = idx & 63, b = idx >> 6;
#pragma unroll
        for (int i = 0; i < NSLOT; i++)
            *(float4*)&sm.vs[i][tid * 4] =
                *(const float4*)&kvp[((size_t)((b * 2 + 1) * NSLOT + i)) * EMB + tid * 4];
        __syncthreads();
        int half = tid >> 7, hs = tid & 127, h = hs >> 4, s = hs & 15;
        for (int ei = 0; ei < 8; ei++) {
            int e = ec * 16 + half * 8 + ei;
            float acc = 0.f;
            if (s < NSLOT) {
                const float* orow = outw + (size_t)e * EMB + h * HD;
                const float* vrow = &sm.vs[s][h * HD];
#pragma unroll 8
                for (int d = 0; d < HD; d++) acc += vrow[d] * orow[d];
            }
            UT[((size_t)b * EMB + e) * 128 + hs] = f2bf(acc);
        }
    }
}

// ---------------- fused scores + softmax + output GEMM ----------------
// Block = 16 t-rows, 256 threads (4 waves), grid 512 (2 blocks/CU).
// BK=128: 8 K-tiles (was 16) -> half the drain/barrier count. Proven single-buffer
// 2-barrier protocol (__syncthreads both sides of STAGE — full memory fence).
// q tile [16][128] f32 (8KB), G tile [128][128] bf16 (32KB), both seg-XOR swizzled
// with inverse-swizzled global sources (rule #21).
#define TBM 16
#define NTQ 8
__global__ __launch_bounds__(256) void score_out(
    const float* __restrict__ q, const ushort_t* __restrict__ G,
    const float* __restrict__ cvec, const ushort_t* __restrict__ UT,
    const float* __restrict__ outb, float* __restrict__ out) {
    __shared__ __align__(16) union {
        struct { float qs[TBM * 128]; ushort_t gs[128 * 128]; } s1;  // 8+32 KB
        ushort_t pl[TBM * 128];                                      // 4 KB
    } sm;

    int tid = threadIdx.x, lane = tid & 63, w = tid >> 6;
    int fr = lane & 15, g = lane >> 4;
    int lb  = xcd_swz(blockIdx.x, gridDim.x);
    int mb0 = lb * TBM;
    int b   = mb0 >> 12;

    const ushort_t* Gb = G + (size_t)b * 128 * EMB;
    int hsb = w * 32;                    // wave w covers heads 2w, 2w+1
    float cv0 = cvec[b * 128 + hsb + fr];
    float cv1 = cvec[b * 128 + hsb + 16 + fr];

    // staging coords (per lane):
    // q: 2 issues; issue i covers rows i*8 + w*2 + (lane>>5), 32 segs of 4 f32/row
    // G: 8 issues; issue j covers rows j*16 + w*4 + (lane>>4), 16 segs of 8 bf16/row
    int qrow = w * 2 + (lane >> 5);
    int qseg = lane & 31;
    int grow = w * 4 + (lane >> 4);
    int gseg = lane & 15;

    f32x4 acc[2] = {};

    for (int t = 0; t < NTQ; t++) {
        __syncthreads();                         // WAR: all reads of prev tile done
#pragma unroll
        for (int i = 0; i < 2; i++) {
            int r = i * 8 + qrow;
            gld16f(q + (size_t)(mb0 + r) * EMB + t * 128 + (qseg ^ r) * 4,
                   &sm.s1.qs[(i * 8 + w * 2) * 128]);
        }
#pragma unroll
        for (int j = 0; j < 8; j++) {
            int r = j * 16 + grow;
            gld16u(Gb + (size_t)r * EMB + t * 128 + (gseg ^ (r & 15)) * 8,
                   &sm.s1.gs[(j * 16 + w * 4) * 128]);
        }
        __syncthreads();                         // full drain: tile visible to all

        __builtin_amdgcn_s_setprio(1);
#pragma unroll
        for (int sub = 0; sub < 4; sub++) {
            int s0 = sub * 8 + g * 2;
            float4 x0 = *(const float4*)&sm.s1.qs[fr * 128 + ((s0)     ^ fr) * 4];
            float4 x1 = *(const float4*)&sm.s1.qs[fr * 128 + ((s0 + 1) ^ fr) * 4];
            bf16x8 af = cvt8(x0, x1);
            int gsg = sub * 4 + g;
#pragma unroll
            for (int n = 0; n < 2; n++) {
                int row = hsb + n * 16 + fr;
                bf16x8 bf_ = *(const bf16x8*)&sm.s1.gs[row * 128 + (gsg ^ fr) * 8];
                acc[n] = __builtin_amdgcn_mfma_f32_16x16x32_bf16(af, bf_, acc[n], 0, 0, 0);
            }
        }
        __builtin_amdgcn_s_setprio(0);
    }

    __syncthreads();   // all s1 reads done before pl-union overwrite

    // ---- softmax (per (t, head) over 16 slots = 16 lanes) -> P in LDS ----
    const float scale = 0.08838834764831845f;   // 1/sqrt(128)
#pragma unroll
    for (int r = 0; r < 4; r++) {
        int row = g * 4 + r;
        int tl  = (mb0 + row) & (SEQ - 1);
        int cse = (tl >= 4 && tl <= SEQ - 4) ? 7 : ((tl < 4) ? tl : tl - (SEQ - 3) + 4);
        float mult = (float)((MULT[cse] >> (fr * 2)) & 3u);
#pragma unroll
        for (int n = 0; n < 2; n++) {
            float vv = (acc[n][r] + (n ? cv1 : cv0)) * scale;
            float vm = (mult != 0.f) ? vv : -1e30f;
#pragma unroll
            for (int sh = 1; sh < 16; sh <<= 1) vm = fmaxf(vm, __shfl_xor(vm, sh, 64));
            float e_ = mult * expf(vv - vm);
            float z = e_;
#pragma unroll
            for (int sh = 1; sh < 16; sh <<= 1) z += __shfl_xor(z, sh, 64);
            int col = hsb + n * 16 + fr;
            int cg  = col >> 3;
            int pg  = (cg & 8) | ((cg & 7) ^ (row & 7));   // granule XOR swizzle
            sm.pl[row * 128 + pg * 8 + (col & 7)] = f2bf(e_ / z);
        }
    }
    __syncthreads();

    // ---- phase 2: out(16 rows x 256 e per wave) = P @ UT^T + outb ----
    const ushort_t* UTb = UT + (size_t)b * EMB * 128;
    int eb = w * 256;
#pragma unroll 4
    for (int n = 0; n < 16; n++) {
        int e = eb + n * 16 + fr;
        f32x4 o2 = {};
#pragma unroll
        for (int kk = 0; kk < 4; kk++) {
            int gi = kk * 4 + g;
            bf16x8 ub = *(const bf16x8*)&UTb[(size_t)e * 128 + kk * 32 + g * 8];
            int pg = (gi & 8) | ((gi & 7) ^ (fr & 7));
            bf16x8 pa = *(const bf16x8*)&sm.pl[fr * 128 + pg * 8];
            o2 = __builtin_amdgcn_mfma_f32_16x16x32_bf16(pa, ub, o2, 0, 0, 0);
        }
        float bn = outb[e];
#pragma unroll
        for (int r = 0; r < 4; r++)
            out[(size_t)(mb0 + g * 4 + r) * EMB + e] = o2[r] + bn;
    }
}

// ---------------- launcher ----------------
extern "C" void kernel_launch(void* const* d_in, const int* in_sizes, int n_in,
                              void* d_out, int out_size, void* d_ws, size_t ws_size,
                              hipStream_t stream) {
    const float* q    = (const float*)d_in[0];
    const float* k    = (const float*)d_in[1];
    const float* v    = (const float*)d_in[2];
    const float* ipw  = (const float*)d_in[3];
    const float* ipb  = (const float*)d_in[4];
    const float* outw = (const float*)d_in[5];
    const float* outb = (const float*)d_in[6];
    float* out = (float*)d_out;

    int Bb = in_sizes[0] / (SEQ * EMB);     // batch (=2)
    int M  = Bb * SEQ;                      // 8192

    float*    kvp  = (float*)d_ws;                                     // Bb*2*15*1024 f32
    ushort_t* G    = (ushort_t*)(kvp + (size_t)Bb * 2 * NSLOT * EMB);  // Bb*128*1024 bf16
    ushort_t* UTm  = G + (size_t)Bb * 128 * EMB;                       // Bb*1024*128 bf16
    float*    cvec = (float*)(UTm + (size_t)Bb * EMB * 128);           // Bb*128 f32

    proj_kv_small<<<dim3(Bb * 2 * 64), dim3(256), 0, stream>>>(k, v, ipw, ipb, kvp);
    gu_pre<<<dim3(Bb * 128 + Bb * 64), dim3(256), 0, stream>>>(
        kvp, ipw, ipb, outw, G, cvec, UTm, Bb * 128);
    score_out<<<dim3(M / TBM), dim3(256), 0, stream>>>(q, G, cvec, UTm, outb, out);
}

// Round 18
// 77.909 us; speedup vs baseline: 1.3744x; 1.1853x over previous
//
#include <hip/hip_runtime.h>
#include <hip/hip_bf16.h>
#include <math.h>

// ---------------- problem constants ----------------
#define SEQ   4096
#define EMB   1024
#define NH    8
#define HD    128
#define NSLOT 15   // distinct gathered positions: 0..10, S-4..S-1 (+1 zero pad slot = 16)

typedef __attribute__((ext_vector_type(8))) short bf16x8;
typedef __attribute__((ext_vector_type(4))) float f32x4;
typedef __attribute__((ext_vector_type(4))) unsigned short ushort4v;
typedef unsigned short ushort_t;

// per-t slot multiplicity masks, 2 bits per slot (slot s at bits 2s..2s+1).
__device__ __constant__ unsigned int MULT[8] = {
    0x00005555u,  // t=0:   slots {0..7}
    0x10015055u,  // t=1:   {0,1,2,3,6,7,8,14}
    0x14050055u,  // t=2:   {0,1,2,3,8,9,13,14}
    0x15100055u,  // t=3:   {0,1,2,3,10,12,13,14}
    0x15800015u,  // t=S-3: {0,1,2, 11x2, 12,13,14}
    0x16800005u,  // t=S-2: {0,1, 11x2, 12x2, 13,14}
    0x1A800001u,  // t=S-1: {0, 11x2, 12x2, 13x2, 14}
    0x15400055u   // interior: {0,1,2,3,11,12,13,14}
};

__device__ __forceinline__ unsigned short f2bf(float x) {
    unsigned int u = __float_as_uint(x);
    return (unsigned short)((u + 0x7FFFu + ((u >> 16) & 1u)) >> 16);
}

// 8x fp32 -> bf16x8 via v_cvt_pk_bf16_f32 (RNE; no builtin on gfx950)
__device__ __forceinline__ bf16x8 cvt8(float4 a, float4 b) {
    union { unsigned int u[4]; bf16x8 v; } r;
    asm("v_cvt_pk_bf16_f32 %0, %1, %2" : "=v"(r.u[0]) : "v"(a.x), "v"(a.y));
    asm("v_cvt_pk_bf16_f32 %0, %1, %2" : "=v"(r.u[1]) : "v"(a.z), "v"(a.w));
    asm("v_cvt_pk_bf16_f32 %0, %1, %2" : "=v"(r.u[2]) : "v"(b.x), "v"(b.y));
    asm("v_cvt_pk_bf16_f32 %0, %1, %2" : "=v"(r.u[3]) : "v"(b.z), "v"(b.w));
    return r.v;
}

// async global->LDS, 16B per lane; lds ptr must be wave-uniform
__device__ __forceinline__ void gld16f(const float* g, float* l) {
    __builtin_amdgcn_global_load_lds(
        (const __attribute__((address_space(1))) unsigned int*)g,
        (__attribute__((address_space(3))) unsigned int*)l, 16, 0, 0);
}
__device__ __forceinline__ void gld16u(const ushort_t* g, ushort_t* l) {
    __builtin_amdgcn_global_load_lds(
        (const __attribute__((address_space(1))) unsigned int*)g,
        (__attribute__((address_space(3))) unsigned int*)l, 16, 0, 0);
}

// bijective chunked XCD swizzle (nwg % 8 == 0)
__device__ __forceinline__ int xcd_swz(int bid, int nwg) {
    int cpx = nwg >> 3;
    return (bid & 7) * cpx + (bid >> 3);
}

// ---------------- small k/v projection (fp32): kvp[(b*2+kv)*15+slot][1024] ----------------
// R16-proven 2-chain variant
__global__ __launch_bounds__(256) void proj_kv_small(
    const float* __restrict__ k, const float* __restrict__ v,
    const float* __restrict__ ipw, const float* __restrict__ ipb,
    float* __restrict__ kvp) {
    int fc  = blockIdx.x & 63;
    int bkv = blockIdx.x >> 6;
    int kv  = bkv & 1;
    int b   = bkv >> 1;

    const float* x0 = (kv ? v : k) + (size_t)b * SEQ * EMB;
    const float* Wm = ipw + (size_t)(1 + kv) * EMB * EMB;
    const float* bb = ipb + (size_t)(1 + kv) * EMB;

    __shared__ __align__(16) float xs[NSLOT][EMB];
    int tid = threadIdx.x;
#pragma unroll
    for (int i = 0; i < NSLOT; i++) {
        int pos = (i < 11) ? i : (SEQ - 4 + (i - 11));
        *(float4*)&xs[i][tid * 4] = *(const float4*)&x0[(size_t)pos * EMB + tid * 4];
    }
    __syncthreads();

    if (tid < 240) {
        int row  = tid >> 4;           // slot 0..14
        int feat = fc * 16 + (tid & 15);
        const float* wrow = Wm + (size_t)feat * EMB;
        float acc0 = 0.f, acc1 = 0.f;
#pragma unroll 4
        for (int kk = 0; kk < EMB; kk += 8) {
            float4 xv0 = *(const float4*)&xs[row][kk];
            float4 wv0 = *(const float4*)&wrow[kk];
            float4 xv1 = *(const float4*)&xs[row][kk + 4];
            float4 wv1 = *(const float4*)&wrow[kk + 4];
            acc0 += xv0.x * wv0.x + xv0.y * wv0.y + xv0.z * wv0.z + xv0.w * wv0.w;
            acc1 += xv1.x * wv1.x + xv1.y * wv1.y + xv1.z * wv1.z + xv1.w * wv1.w;
        }
        kvp[((size_t)((b * 2 + kv) * NSLOT + row)) * EMB + feat] = acc0 + acc1 + bb[feat];
    }
}

// ---------------- merged precompute: G/cvec (gmat part) + UT (umat part) ----------------
union GUShared {
    struct { float xs[HD]; float red[HD]; } gm;
    float vs[NSLOT][EMB + 4];
};
__global__ __launch_bounds__(256) void gu_pre(
    const float* __restrict__ kvp, const float* __restrict__ ipw,
    const float* __restrict__ ipb, const float* __restrict__ outw,
    ushort_t* __restrict__ G, float* __restrict__ cvec,
    ushort_t* __restrict__ UT, int nGm) {
    __shared__ __align__(16) GUShared sm;
    int tid = threadIdx.x;

    if (blockIdx.x < (unsigned)nGm) {
        // ---- gmat (R14-verbatim): G[b][hs][e] = Wq_h^T kh_h[s]; cvec = bq_h . kh_h[s] ----
        int hs = blockIdx.x & 127, b = blockIdx.x >> 7;
        int h = hs >> 4, s = hs & 15;
        if (tid < HD)
            sm.gm.xs[tid] = (s < NSLOT)
                ? kvp[((size_t)((b * 2 + 0) * NSLOT + s)) * EMB + h * HD + tid] : 0.f;
        __syncthreads();
        int e0 = tid * 4;
        float a0 = 0.f, a1 = 0.f, a2 = 0.f, a3 = 0.f;
#pragma unroll 8
        for (int d = 0; d < HD; d++) {
            float xv = sm.gm.xs[d];
            const float* wr_ = ipw + (size_t)(h * HD + d) * EMB + e0;
            a0 += xv * wr_[0]; a1 += xv * wr_[1]; a2 += xv * wr_[2]; a3 += xv * wr_[3];
        }
        ushort4v gv; gv[0] = f2bf(a0); gv[1] = f2bf(a1); gv[2] = f2bf(a2); gv[3] = f2bf(a3);
        *(ushort4v*)&G[((size_t)b * 128 + hs) * EMB + e0] = gv;

        if (tid < HD) sm.gm.red[tid] = sm.gm.xs[tid] * ipb[h * HD + tid];
        __syncthreads();
        if (tid < 64) {
            float vsum = sm.gm.red[tid] + sm.gm.red[tid + 64];
            vsum += __shfl_down(vsum, 32, 64); vsum += __shfl_down(vsum, 16, 64);
            vsum += __shfl_down(vsum, 8, 64);  vsum += __shfl_down(vsum, 4, 64);
            vsum += __shfl_down(vsum, 2, 64);  vsum += __shfl_down(vsum, 1, 64);
            if (tid == 0) cvec[b * 128 + hs] = vsum;
        }
    } else {
        // ---- umat: UT[b][e][hs] = vh_h[s] . Wo[e, hHD..]  (LDS-staged vs) ----
        // dc-outer / ei-inner: 8 independent acc chains, float4 loads, 16 loads in flight
        int idx = blockIdx.x - nGm;
        int ec = idx & 63, b = idx >> 6;
#pragma unroll
        for (int i = 0; i < NSLOT; i++)
            *(float4*)&sm.vs[i][tid * 4] =
                *(const float4*)&kvp[((size_t)((b * 2 + 1) * NSLOT + i)) * EMB + tid * 4];
        __syncthreads();
        int half = tid >> 7, hs = tid & 127, h = hs >> 4, s = hs & 15;
        int e0 = ec * 16 + half * 8;
        const float* ob = outw + (size_t)e0 * EMB + h * HD;   // rows e0..e0+7
        float acc[8] = {0.f, 0.f, 0.f, 0.f, 0.f, 0.f, 0.f, 0.f};
        if (s < NSLOT) {
            const float* vrow = &sm.vs[s][h * HD];
            for (int dc = 0; dc < HD; dc += 8) {
                float4 v0 = *(const float4*)&vrow[dc];
                float4 v1 = *(const float4*)&vrow[dc + 4];
#pragma unroll
                for (int ei = 0; ei < 8; ei++) {
                    const float* orow = ob + (size_t)ei * EMB;
                    float4 o0 = *(const float4*)&orow[dc];
                    float4 o1 = *(const float4*)&orow[dc + 4];
                    acc[ei] += o0.x * v0.x + o0.y * v0.y + o0.z * v0.z + o0.w * v0.w
                             + o1.x * v1.x + o1.y * v1.y + o1.z * v1.z + o1.w * v1.w;
                }
            }
        }
#pragma unroll
        for (int ei = 0; ei < 8; ei++)
            UT[((size_t)b * EMB + e0 + ei) * 128 + hs] = f2bf(acc[ei]);
    }
}

// ---------------- fused scores + softmax + output GEMM (R17-verbatim, PASSED) ----------------
// Block = 16 t-rows, 256 threads (4 waves), grid 512 (2 blocks/CU). BK=128: 8 K-tiles.
// Proven single-buffer 2-barrier protocol (__syncthreads both sides of STAGE).
#define TBM 16
#define NTQ 8
__global__ __launch_bounds__(256) void score_out(
    const float* __restrict__ q, const ushort_t* __restrict__ G,
    const float* __restrict__ cvec, const ushort_t* __restrict__ UT,
    const float* __restrict__ outb, float* __restrict__ out) {
    __shared__ __align__(16) union {
        struct { float qs[TBM * 128]; ushort_t gs[128 * 128]; } s1;  // 8+32 KB
        ushort_t pl[TBM * 128];                                      // 4 KB
    } sm;

    int tid = threadIdx.x, lane = tid & 63, w = tid >> 6;
    int fr = lane & 15, g = lane >> 4;
    int lb  = xcd_swz(blockIdx.x, gridDim.x);
    int mb0 = lb * TBM;
    int b   = mb0 >> 12;

    const ushort_t* Gb = G + (size_t)b * 128 * EMB;
    int hsb = w * 32;                    // wave w covers heads 2w, 2w+1
    float cv0 = cvec[b * 128 + hsb + fr];
    float cv1 = cvec[b * 128 + hsb + 16 + fr];

    // staging coords (per lane):
    int qrow = w * 2 + (lane >> 5);
    int qseg = lane & 31;
    int grow = w * 4 + (lane >> 4);
    int gseg = lane & 15;

    f32x4 acc[2] = {};

    for (int t = 0; t < NTQ; t++) {
        __syncthreads();                         // WAR: all reads of prev tile done
#pragma unroll
        for (int i = 0; i < 2; i++) {
            int r = i * 8 + qrow;
            gld16f(q + (size_t)(mb0 + r) * EMB + t * 128 + (qseg ^ r) * 4,
                   &sm.s1.qs[(i * 8 + w * 2) * 128]);
        }
#pragma unroll
        for (int j = 0; j < 8; j++) {
            int r = j * 16 + grow;
            gld16u(Gb + (size_t)r * EMB + t * 128 + (gseg ^ (r & 15)) * 8,
                   &sm.s1.gs[(j * 16 + w * 4) * 128]);
        }
        __syncthreads();                         // full drain: tile visible to all

        __builtin_amdgcn_s_setprio(1);
#pragma unroll
        for (int sub = 0; sub < 4; sub++) {
            int s0 = sub * 8 + g * 2;
            float4 x0 = *(const float4*)&sm.s1.qs[fr * 128 + ((s0)     ^ fr) * 4];
            float4 x1 = *(const float4*)&sm.s1.qs[fr * 128 + ((s0 + 1) ^ fr) * 4];
            bf16x8 af = cvt8(x0, x1);
            int gsg = sub * 4 + g;
#pragma unroll
            for (int n = 0; n < 2; n++) {
                int row = hsb + n * 16 + fr;
                bf16x8 bf_ = *(const bf16x8*)&sm.s1.gs[row * 128 + (gsg ^ fr) * 8];
                acc[n] = __builtin_amdgcn_mfma_f32_16x16x32_bf16(af, bf_, acc[n], 0, 0, 0);
            }
        }
        __builtin_amdgcn_s_setprio(0);
    }

    __syncthreads();   // all s1 reads done before pl-union overwrite

    // ---- softmax (per (t, head) over 16 slots = 16 lanes) -> P in LDS ----
    const float scale = 0.08838834764831845f;   // 1/sqrt(128)
#pragma unroll
    for (int r = 0; r < 4; r++) {
        int row = g * 4 + r;
        int tl  = (mb0 + row) & (SEQ - 1);
        int cse = (tl >= 4 && tl <= SEQ - 4) ? 7 : ((tl < 4) ? tl : tl - (SEQ - 3) + 4);
        float mult = (float)((MULT[cse] >> (fr * 2)) & 3u);
#pragma unroll
        for (int n = 0; n < 2; n++) {
            float vv = (acc[n][r] + (n ? cv1 : cv0)) * scale;
            float vm = (mult != 0.f) ? vv : -1e30f;
#pragma unroll
            for (int sh = 1; sh < 16; sh <<= 1) vm = fmaxf(vm, __shfl_xor(vm, sh, 64));
            float e_ = mult * expf(vv - vm);
            float z = e_;
#pragma unroll
            for (int sh = 1; sh < 16; sh <<= 1) z += __shfl_xor(z, sh, 64);
            int col = hsb + n * 16 + fr;
            int cg  = col >> 3;
            int pg  = (cg & 8) | ((cg & 7) ^ (row & 7));   // granule XOR swizzle
            sm.pl[row * 128 + pg * 8 + (col & 7)] = f2bf(e_ / z);
        }
    }
    __syncthreads();

    // ---- phase 2: out(16 rows x 256 e per wave) = P @ UT^T + outb ----
    const ushort_t* UTb = UT + (size_t)b * EMB * 128;
    int eb = w * 256;
#pragma unroll 4
    for (int n = 0; n < 16; n++) {
        int e = eb + n * 16 + fr;
        f32x4 o2 = {};
#pragma unroll
        for (int kk = 0; kk < 4; kk++) {
            int gi = kk * 4 + g;
            bf16x8 ub = *(const bf16x8*)&UTb[(size_t)e * 128 + kk * 32 + g * 8];
            int pg = (gi & 8) | ((gi & 7) ^ (fr & 7));
            bf16x8 pa = *(const bf16x8*)&sm.pl[fr * 128 + pg * 8];
            o2 = __builtin_amdgcn_mfma_f32_16x16x32_bf16(pa, ub, o2, 0, 0, 0);
        }
        float bn = outb[e];
#pragma unroll
        for (int r = 0; r < 4; r++)
            out[(size_t)(mb0 + g * 4 + r) * EMB + e] = o2[r] + bn;
    }
}

// ---------------- launcher ----------------
extern "C" void kernel_launch(void* const* d_in, const int* in_sizes, int n_in,
                              void* d_out, int out_size, void* d_ws, size_t ws_size,
                              hipStream_t stream) {
    const float* q    = (const float*)d_in[0];
    const float* k    = (const float*)d_in[1];
    const float* v    = (const float*)d_in[2];
    const float* ipw  = (const float*)d_in[3];
    const float* ipb  = (const float*)d_in[4];
    const float* outw = (const float*)d_in[5];
    const float* outb = (const float*)d_in[6];
    float* out = (float*)d_out;

    int Bb = in_sizes[0] / (SEQ * EMB);     // batch (=2)
    int M  = Bb * SEQ;                      // 8192

    float*    kvp  = (float*)d_ws;                                     // Bb*2*15*1024 f32
    ushort_t* G    = (ushort_t*)(kvp + (size_t)Bb * 2 * NSLOT * EMB);  // Bb*128*1024 bf16
    ushort_t* UTm  = G + (size_t)Bb * 128 * EMB;                       // Bb*1024*128 bf16
    float*    cvec = (float*)(UTm + (size_t)Bb * EMB * 128);           // Bb*128 f32

    proj_kv_small<<<dim3(Bb * 2 * 64), dim3(256), 0, stream>>>(k, v, ipw, ipb, kvp);
    gu_pre<<<dim3(Bb * 128 + Bb * 64), dim3(256), 0, stream>>>(
        kvp, ipw, ipb, outw, G, cvec, UTm, Bb * 128);
    score_out<<<dim3(M / TBM), dim3(256), 0, stream>>>(q, G, cvec, UTm, outb, out);
}